// Round 1
// baseline (1446.957 us; speedup 1.0000x reference)
//
#include <hip/hip_runtime.h>
#include <cstdint>
#include <cstddef>

// Problem constants (fixed by setup_inputs): B*S=8192, I=4096, O=11008, n_g=64
#define M_DIM 8192
#define N_DIM 11008
#define K_DIM 4096

typedef __attribute__((ext_vector_type(8))) __bf16 bf16x8;
typedef __attribute__((ext_vector_type(4))) float f32x4;
typedef __attribute__((ext_vector_type(8))) unsigned short ushort8v;

__device__ __forceinline__ unsigned short bf16rn(float f) {
  unsigned int u = __float_as_uint(f);
  u += 0x7FFFu + ((u >> 16) & 1u);   // round-to-nearest-even
  return (unsigned short)(u >> 16);
}

// ---------------- Pass 1a: x fp32 -> bf16 ----------------
// 33,554,432 elements, 8 per thread -> 16384 blocks x 256
__global__ void cvt_x_kernel(const float* __restrict__ x,
                             unsigned short* __restrict__ xb) {
  const int i = (blockIdx.x * 256 + threadIdx.x) * 8;
  const float4 a = *(const float4*)(x + i);
  const float4 b = *(const float4*)(x + i + 4);
  ushort8v o;
  o[0] = bf16rn(a.x); o[1] = bf16rn(a.y); o[2] = bf16rn(a.z); o[3] = bf16rn(a.w);
  o[4] = bf16rn(b.x); o[5] = bf16rn(b.y); o[6] = bf16rn(b.z); o[7] = bf16rn(b.w);
  *(ushort8v*)(xb + i) = o;
}

// ---------------- Pass 1b: dequantize W -> bf16 [O, I] K-major ----------------
// Each int32 word j holds col 2j (lo nibble) and col 2j+1 (hi nibble).
// group size = 64 cols; thread handles 4 words = 8 cols (single group).
// total threads = 11008 * 512 = 5,636,096 -> 22016 blocks x 256
__global__ void dequant_w_kernel(const int* __restrict__ wq,
                                 const float* __restrict__ scales,
                                 const float* __restrict__ zeros,
                                 const float* __restrict__ csc,
                                 unsigned short* __restrict__ wb) {
  const int gid = blockIdx.x * 256 + threadIdx.x;
  const int row = gid >> 9;      // / 512
  const int j4  = gid & 511;     // 4-word position in row
  const int4 q = *(const int4*)(wq + row * 2048 + j4 * 4);
  const int g = j4 >> 3;         // (j4*8)/64
  const float s = scales[row * 64 + g];
  const float z = zeros[row * 64 + g];
  const int col = j4 * 8;
  const float4 c0 = *(const float4*)(csc + col);
  const float4 c1 = *(const float4*)(csc + col + 4);
  ushort8v o;
  o[0] = bf16rn((s * (float)( q.x        & 15) + z) * c0.x);
  o[1] = bf16rn((s * (float)((q.x >> 4)  & 15) + z) * c0.y);
  o[2] = bf16rn((s * (float)( q.y        & 15) + z) * c0.z);
  o[3] = bf16rn((s * (float)((q.y >> 4)  & 15) + z) * c0.w);
  o[4] = bf16rn((s * (float)( q.z        & 15) + z) * c1.x);
  o[5] = bf16rn((s * (float)((q.z >> 4)  & 15) + z) * c1.y);
  o[6] = bf16rn((s * (float)( q.w        & 15) + z) * c1.z);
  o[7] = bf16rn((s * (float)((q.w >> 4)  & 15) + z) * c1.w);
  *(ushort8v*)(wb + row * 4096 + col) = o;
}

// ---------------- Pass 2: bf16 GEMM (m97 structure) ----------------
// C[M,N] = A[M,K] * B[N,K]^T + bias;  128x128 tile, BK=32, 256 threads (4 waves),
// each wave computes 64x64 via 4x4 mfma_f32_16x16x32_bf16.
__device__ __forceinline__ void gld_lds16(void* gp, void* lp) {
  __builtin_amdgcn_global_load_lds(
      (__attribute__((address_space(1))) void*)gp,
      (__attribute__((address_space(3))) void*)lp,
      16, 0, 0);
}

__global__ __launch_bounds__(256) void gemm_kernel(
    const unsigned short* __restrict__ A,   // x bf16 [M,K]
    const unsigned short* __restrict__ B,   // w bf16 [N,K]
    const float* __restrict__ bias,         // [N]
    float* __restrict__ C) {                // [M,N] fp32
  __shared__ unsigned short As[128 * 32];   // row-major [row][k], 64B rows
  __shared__ unsigned short Bs[128 * 32];

  const int tid  = threadIdx.x;
  const int lane = tid & 63;
  const int wave = tid >> 6;
  const int bm = blockIdx.y * 128;
  const int bn = blockIdx.x * 128;
  const int wm = (wave & 1) * 64;           // wave's M offset in tile
  const int wn = (wave >> 1) * 64;          // wave's N offset in tile

  f32x4 acc[4][4] = {};

  // Staging: wave w stages rows [w*32, w*32+32) of both tiles, two 1KB wave-loads
  // each. global_load_lds dest = wave-uniform base + lane*16 (no padding!).
  const int srow = wave * 32 + (lane >> 2);
  const int skol = (lane & 3) * 8;
  const unsigned short* gA0 = A + (size_t)(bm + srow) * K_DIM + skol;
  const unsigned short* gA1 = gA0 + 16 * K_DIM;
  const unsigned short* gB0 = B + (size_t)(bn + srow) * K_DIM + skol;
  const unsigned short* gB1 = gB0 + 16 * K_DIM;
  unsigned short* lA0 = &As[wave * 1024];
  unsigned short* lA1 = &As[wave * 1024 + 512];
  unsigned short* lB0 = &Bs[wave * 1024];
  unsigned short* lB1 = &Bs[wave * 1024 + 512];

  const int fr = lane & 15;          // fragment row (m or n within 16)
  const int fk = (lane >> 4) * 8;    // fragment k offset (quad*8)

  for (int kk = 0; kk < K_DIM; kk += 32) {
    gld_lds16((void*)(gA0 + kk), lA0);
    gld_lds16((void*)(gA1 + kk), lA1);
    gld_lds16((void*)(gB0 + kk), lB0);
    gld_lds16((void*)(gB1 + kk), lB1);
    __syncthreads();   // drains vmcnt(0): LDS tiles complete

    bf16x8 af[4], bfr[4];
#pragma unroll
    for (int i = 0; i < 4; ++i)
      af[i] = *(const bf16x8*)&As[(wm + i * 16 + fr) * 32 + fk];
#pragma unroll
    for (int j = 0; j < 4; ++j)
      bfr[j] = *(const bf16x8*)&Bs[(wn + j * 16 + fr) * 32 + fk];
#pragma unroll
    for (int i = 0; i < 4; ++i)
#pragma unroll
      for (int j = 0; j < 4; ++j)
        acc[i][j] = __builtin_amdgcn_mfma_f32_16x16x32_bf16(af[i], bfr[j],
                                                            acc[i][j], 0, 0, 0);
    __syncthreads();   // all waves done reading before next overwrite
  }

  // Epilogue: C/D layout col=lane&15, row=(lane>>4)*4+reg (m89/m91-verified)
  const int col0 = bn + wn + fr;
  const int row0 = bm + wm + (lane >> 4) * 4;
#pragma unroll
  for (int j = 0; j < 4; ++j) {
    const float bv = bias[col0 + j * 16];
#pragma unroll
    for (int i = 0; i < 4; ++i) {
#pragma unroll
      for (int r = 0; r < 4; ++r) {
        C[(size_t)(row0 + i * 16 + r) * N_DIM + (col0 + j * 16)] =
            acc[i][j][r] + bv;
      }
    }
  }
}

extern "C" void kernel_launch(void* const* d_in, const int* in_sizes, int n_in,
                              void* d_out, int out_size, void* d_ws, size_t ws_size,
                              hipStream_t stream) {
  const float* x      = (const float*)d_in[0];  // [4,2048,4096] fp32
  const int*   wq     = (const int*)d_in[1];    // [11008,2048] int32
  const float* scales = (const float*)d_in[2];  // [11008,64]
  const float* zeros  = (const float*)d_in[3];  // [11008,64]
  const float* csc    = (const float*)d_in[4];  // [4096]
  const float* bias   = (const float*)d_in[5];  // [11008]
  float* out = (float*)d_out;                   // [4,2048,11008] fp32

  // Workspace layout: xb (67,108,864 B) then wb (90,177,536 B) = 150 MiB
  unsigned short* xb = (unsigned short*)d_ws;
  unsigned short* wb = (unsigned short*)((char*)d_ws + (size_t)M_DIM * K_DIM * 2);

  cvt_x_kernel<<<16384, 256, 0, stream>>>(x, xb);
  dequant_w_kernel<<<22016, 256, 0, stream>>>(wq, scales, zeros, csc, wb);
  dim3 grid(N_DIM / 128, M_DIM / 128);  // 86 x 64 = 5504 blocks
  gemm_kernel<<<grid, 256, 0, stream>>>(xb, wb, bias, out);
}